// Round 1
// baseline (355.758 us; speedup 1.0000x reference)
//
#include <hip/hip_runtime.h>
#include <math.h>

#define NSWEEP 8
static constexpr int Bn = 32768;

// ws layout (floats)
#define WS_COEF  0        // [64][28] : per n {w, qc[3], cb[24]}  (cb idx = k*3+j)
#define WS_G     1792     // [8][8]
#define WS_g     1856     // [8]
#define WS_BW    1864     // [24]  b_w[k*3+m]
#define WS_Q00   1888
#define WS_WSUM  1889
#define WS_BATCH 1920     // [130][Bn] : 0..54 Qsym, 55..126 FG[k*9+e], 127..129 y_w

__host__ __device__ constexpr int tidx(int i, int j) { return i*10 - i*(i+1)/2 + j; } // i<=j
__host__ __device__ constexpr int tmm(int i, int j)  { return (i<j) ? tidx(i,j) : tidx(j,i); }

// ---------------- K1: precompute (1 block, 64 threads) ----------------
__global__ void k_pre(const float* __restrict__ bb, const float* __restrict__ w,
                      const float* __restrict__ lam, float* __restrict__ ws)
{
  __shared__ float s_w[64], s_sw[64], s_bw[24], s_barb[64][24];
  __shared__ float s_BtB[64];
  __shared__ float s_G[64], s_g[8], s_wsum;
  const int t = threadIdx.x;
  s_w[t]  = w[t];
  s_sw[t] = sqrtf(fmaxf(s_w[t], 0.0f));
  __syncthreads();
  if (t == 0) { float a = 0; for (int n = 0; n < 64; n++) a += s_w[n]; s_wsum = a; }
  __syncthreads();
  const float wsum = s_wsum;
  if (t < 24) {                       // b_w[k*3+m]
    float a = 0;
    for (int n = 0; n < 64; n++) a += bb[t*64 + n] * s_w[n];
    s_bw[t] = a / wsum;
  }
  __syncthreads();
  for (int km = 0; km < 24; ++km)     // bar_b[n][km], t = n
    s_barb[t][km] = s_sw[t] * (bb[km*64 + t] - s_bw[km]);
  __syncthreads();
  {                                    // BtB, t = k*8+k2
    int k = t >> 3, k2 = t & 7;
    float a = 0;
    for (int n = 0; n < 64; n++)
      for (int j = 0; j < 3; j++)
        a += s_barb[n][k*3 + j] * s_barb[n][k2*3 + j];
    s_BtB[t] = a;
  }
  __syncthreads();
  if (t == 0) {
    const float lv = lam[0];
    float A[8][8], Iv[8][8];
#pragma unroll
    for (int i = 0; i < 8; i++)
#pragma unroll
      for (int j = 0; j < 8; j++) {
        A[i][j]  = 2.0f * (s_BtB[i*8 + j] + ((i == j) ? lv : 0.0f));
        Iv[i][j] = (i == j) ? 1.0f : 0.0f;
      }
    // Gauss-Jordan (bar_H is SPD; no pivoting needed)
#pragma unroll
    for (int k = 0; k < 8; k++) {
      float piv = 1.0f / A[k][k];
#pragma unroll
      for (int j = 0; j < 8; j++) { A[k][j] *= piv; Iv[k][j] *= piv; }
#pragma unroll
      for (int i = 0; i < 8; i++) {
        if (i == k) continue;
        float f = A[i][k];
#pragma unroll
        for (int j = 0; j < 8; j++) { A[i][j] -= f * A[k][j]; Iv[i][j] -= f * Iv[k][j]; }
      }
    }
    float u[8]; float s = 0;
#pragma unroll
    for (int i = 0; i < 8; i++) {
      float a = 0;
#pragma unroll
      for (int j = 0; j < 8; j++) a += Iv[i][j];
      u[i] = a; s += a;
    }
#pragma unroll
    for (int i = 0; i < 8; i++) s_g[i] = u[i] / s;
    float q00 = 0.0f;
#pragma unroll
    for (int i = 0; i < 8; i++)
#pragma unroll
      for (int j = 0; j < 8; j++) {
        s_G[i*8 + j] = Iv[i][j] - u[i]*u[j]/s;
        q00 += s_g[i] * (s_BtB[i*8 + j] + ((i == j) ? lv : 0.0f)) * s_g[j];
      }
    ws[WS_Q00]  = q00;
    ws[WS_WSUM] = wsum;
  }
  __syncthreads();
  if (t < 8)  ws[WS_g + t]  = s_g[t];
  if (t < 24) ws[WS_BW + t] = s_bw[t];
  ws[WS_G + t] = s_G[t];
  {                                     // packed per-n coefficients, t = n
    float* c = ws + WS_COEF + t*28;
    c[0] = s_w[t];
    float qc[3] = {0, 0, 0};
#pragma unroll
    for (int km = 0; km < 24; km++) {
      float cb = s_sw[t] * s_barb[t][km];   // = w[n]*(b - b_w)
      c[4 + km] = cb;
      qc[km % 3] += s_g[km / 3] * cb;
    }
    c[1] = qc[0]; c[2] = qc[1]; c[3] = qc[2];
  }
}

// ---------------- K2: per-batch Q build ----------------
__global__ __launch_bounds__(256) void k_build(const float* __restrict__ y, float* ws)
{
  const int b = blockIdx.x * 256 + threadIdx.x;
  const float* yb = y + (size_t)b * 192;
  const float* coef = ws + WS_COEF;
  float F[24][3];           // [k*3+j][m]
  float qt[3][3];           // [j][m]
  float gw[6];              // (00,01,02,11,12,22)
  float ywa[3] = {0, 0, 0};
#pragma unroll
  for (int i = 0; i < 24; i++) { F[i][0] = 0; F[i][1] = 0; F[i][2] = 0; }
#pragma unroll
  for (int i = 0; i < 9; i++) qt[i/3][i%3] = 0;
#pragma unroll
  for (int i = 0; i < 6; i++) gw[i] = 0;

  for (int n4 = 0; n4 < 16; n4++) {
    float4 v0 = reinterpret_cast<const float4*>(yb)[n4];
    float4 v1 = reinterpret_cast<const float4*>(yb + 64)[n4];
    float4 v2 = reinterpret_cast<const float4*>(yb + 128)[n4];
    float a0[4] = {v0.x, v0.y, v0.z, v0.w};
    float a1[4] = {v1.x, v1.y, v1.z, v1.w};
    float a2[4] = {v2.x, v2.y, v2.z, v2.w};
#pragma unroll
    for (int l = 0; l < 4; l++) {
      const int n = 4*n4 + l;
      const float* c = coef + n*28;
      float ym0 = a0[l], ym1 = a1[l], ym2 = a2[l];
      float wn  = c[0];
      float wy0 = wn*ym0, wy1 = wn*ym1, wy2 = wn*ym2;
      ywa[0] += wy0; ywa[1] += wy1; ywa[2] += wy2;
      gw[0] += wy0*ym0; gw[1] += wy0*ym1; gw[2] += wy0*ym2;
      gw[3] += wy1*ym1; gw[4] += wy1*ym2; gw[5] += wy2*ym2;
#pragma unroll
      for (int j = 0; j < 3; j++) {
        float qcv = c[1 + j];
        qt[j][0] += qcv*ym0; qt[j][1] += qcv*ym1; qt[j][2] += qcv*ym2;
      }
#pragma unroll
      for (int kj = 0; kj < 24; kj++) {
        float cb = c[4 + kj];
        F[kj][0] += cb*ym0; F[kj][1] += cb*ym1; F[kj][2] += cb*ym2;
      }
    }
  }
  const float wsum = ws[WS_WSUM];
  const float q00  = ws[WS_Q00];
  const float iws  = 1.0f / wsum;
  float yw[3] = {ywa[0]*iws, ywa[1]*iws, ywa[2]*iws};
  float Gram[3][3];
  Gram[0][0] = gw[0] - ywa[0]*ywa[0]*iws;
  Gram[0][1] = Gram[1][0] = gw[1] - ywa[0]*ywa[1]*iws;
  Gram[0][2] = Gram[2][0] = gw[2] - ywa[0]*ywa[2]*iws;
  Gram[1][1] = gw[3] - ywa[1]*ywa[1]*iws;
  Gram[1][2] = Gram[2][1] = gw[4] - ywa[1]*ywa[2]*iws;
  Gram[2][2] = gw[5] - ywa[2]*ywa[2]*iws;

  float Gm[64];
#pragma unroll
  for (int i = 0; i < 64; i++) Gm[i] = ws[WS_G + i];
  float FG[8][9];                         // FG[k2][e] = sum_k G[k][k2]*F[k][e]
#pragma unroll
  for (int k2 = 0; k2 < 8; k2++)
#pragma unroll
    for (int e = 0; e < 9; e++) {
      const int j = e / 3, m = e % 3;
      float a = 0;
#pragma unroll
      for (int k = 0; k < 8; k++) a += Gm[k*8 + k2] * F[k*3 + j][m];
      FG[k2][e] = a;
    }
  float q[55];
  q[tidx(0,0)] = q00;
#pragma unroll
  for (int e = 0; e < 9; e++) q[tidx(0, 1 + e)] = -qt[e/3][e%3];
#pragma unroll
  for (int e = 0; e < 9; e++)
#pragma unroll
    for (int f = e; f < 9; f++) {
      const int j = e/3, m = e%3, j2 = f/3, m2 = f%3;
      float a = 0;
#pragma unroll
      for (int k = 0; k < 8; k++) a += FG[k][e] * F[k*3 + j2][m2];
      q[tidx(1 + e, 1 + f)] = -2.0f*a + ((j == j2) ? Gram[m][m2] : 0.0f);
    }
  float* wb = ws + WS_BATCH;
#pragma unroll
  for (int i = 0; i < 55; i++) wb[(size_t)i*Bn + b] = q[i];
#pragma unroll
  for (int k = 0; k < 8; k++)
#pragma unroll
    for (int e = 0; e < 9; e++)
      wb[(size_t)(55 + k*9 + e)*Bn + b] = FG[k][e];
#pragma unroll
  for (int m = 0; m < 3; m++) wb[(size_t)(127 + m)*Bn + b] = yw[m];
}

// ---------------- K3: per-batch Jacobi eigensolve + outputs ----------------
__global__ __launch_bounds__(64, 1) void k_eig(const float* __restrict__ ws,
                                               float* __restrict__ out)
{
  const int b = blockIdx.x * 64 + threadIdx.x;
  const float* wb = ws + WS_BATCH;
  float A[55];
#pragma unroll
  for (int i = 0; i < 55; i++) A[i] = wb[(size_t)i*Bn + b];
  float V[100];
#pragma unroll
  for (int i = 0; i < 100; i++) V[i] = (i % 11 == 0) ? 1.0f : 0.0f;

  for (int sweep = 0; sweep < NSWEEP; ++sweep) {
#pragma unroll
    for (int p = 0; p < 10; p++) {
#pragma unroll
      for (int q = p + 1; q < 10; q++) {
        float apq = A[tidx(p,q)];
        float app = A[tidx(p,p)];
        float aqq = A[tidx(q,q)];
        float theta = 0.5f * (aqq - app) / apq;
        float tt = 1.0f / (fabsf(theta) + sqrtf(theta*theta + 1.0f));
        tt = (theta < 0.0f) ? -tt : tt;
        tt = (apq == 0.0f) ? 0.0f : tt;       // guard 0/0 NaN
        float cth = 1.0f / sqrtf(tt*tt + 1.0f);
        float sth = tt * cth;
        A[tidx(p,p)] = app - tt*apq;
        A[tidx(q,q)] = aqq + tt*apq;
        A[tidx(p,q)] = 0.0f;
#pragma unroll
        for (int i = 0; i < 10; i++) {
          if (i == p || i == q) continue;
          float aip = A[tmm(i,p)];
          float aiq = A[tmm(i,q)];
          A[tmm(i,p)] = cth*aip - sth*aiq;
          A[tmm(i,q)] = sth*aip + cth*aiq;
        }
#pragma unroll
        for (int i = 0; i < 10; i++) {
          float vip = V[i*10 + p], viq = V[i*10 + q];
          V[i*10 + p] = cth*vip - sth*viq;
          V[i*10 + q] = sth*vip + cth*viq;
        }
      }
    }
  }
  // argmin eigenvalue
  float dmin = A[tidx(0,0)]; int jm = 0;
#pragma unroll
  for (int j = 1; j < 10; j++) {
    float d = A[tidx(j,j)];
    if (d < dmin) { dmin = d; jm = j; }
  }
  float v[10];
#pragma unroll
  for (int i = 0; i < 10; i++) {
    float x = V[i*10];
#pragma unroll
    for (int j = 1; j < 10; j++) x = (jm == j) ? V[i*10 + j] : x;
    v[i] = x;
  }
  const float inv0 = 1.0f / v[0];
  float R[3][3];
#pragma unroll
  for (int r = 0; r < 3; r++)
#pragma unroll
    for (int cc = 0; cc < 3; cc++)
      R[r][cc] = v[1 + 3*cc + r] * inv0;
  // c = 2*inv0*sum_e v[1+e]*FG[k][e] + g[k]
  float cvec[8];
#pragma unroll
  for (int k = 0; k < 8; k++) {
    float a = 0;
#pragma unroll
    for (int e = 0; e < 9; e++) a += v[1 + e] * wb[(size_t)(55 + k*9 + e)*Bn + b];
    cvec[k] = 2.0f * inv0 * a + ws[WS_g + k];
  }
  float um[3] = {0, 0, 0};
#pragma unroll
  for (int k = 0; k < 8; k++) {
    float ck = cvec[k];
    um[0] += ws[WS_BW + k*3 + 0] * ck;
    um[1] += ws[WS_BW + k*3 + 1] * ck;
    um[2] += ws[WS_BW + k*3 + 2] * ck;
  }
#pragma unroll
  for (int r = 0; r < 3; r++)
#pragma unroll
    for (int cc = 0; cc < 3; cc++)
      out[(size_t)b*9 + r*3 + cc] = R[r][cc];
#pragma unroll
  for (int r = 0; r < 3; r++) {
    float yw = wb[(size_t)(127 + r)*Bn + b];
    out[(size_t)9*Bn + b*3 + r] = yw - (R[r][0]*um[0] + R[r][1]*um[1] + R[r][2]*um[2]);
  }
#pragma unroll
  for (int k = 0; k < 8; k++)
    out[(size_t)12*Bn + b*8 + k] = cvec[k];
}

extern "C" void kernel_launch(void* const* d_in, const int* in_sizes, int n_in,
                              void* d_out, int out_size, void* d_ws, size_t ws_size,
                              hipStream_t stream) {
  const float* y   = (const float*)d_in[0];
  const float* bb  = (const float*)d_in[1];
  const float* w   = (const float*)d_in[2];
  const float* lam = (const float*)d_in[3];
  float* ws  = (float*)d_ws;
  float* out = (float*)d_out;
  k_pre  <<<1,        64, 0, stream>>>(bb, w, lam, ws);
  k_build<<<Bn/256,  256, 0, stream>>>(y, ws);
  k_eig  <<<Bn/64,    64, 0, stream>>>(ws, out);
}

// Round 2
// 136.604 us; speedup vs baseline: 2.6043x; 2.6043x over previous
//
#include <hip/hip_runtime.h>
#include <math.h>

#define NSWEEP 6
static constexpr int Bn = 32768;

// ws layout (floats)
#define WS_COEF  0        // [64][28] : per n {w, qc[3], cb[24]}  (cb idx = k*3+j)
#define WS_G     1792     // [8][8]
#define WS_g     1856     // [8]
#define WS_BW    1864     // [24]  b_w[k*3+m]
#define WS_Q00   1888
#define WS_WSUM  1889
#define WS_BATCH 1920     // [130][Bn] : 0..54 Qsym(upper), 55..126 FG[k*9+e], 127..129 y_w

__host__ __device__ constexpr int tidx(int i, int j) { return i*10 - i*(i+1)/2 + j; } // i<=j (upper packed)
__host__ __device__ constexpr int tmm(int i, int j)  { return (i<j) ? tidx(i,j) : tidx(j,i); }
__host__ __device__ constexpr int lidx(int i, int j) { return i*(i+1)/2 + j; }        // i>=j (lower packed)

// ---------------- K1: precompute (1 block, 64 threads) ----------------
__global__ void k_pre(const float* __restrict__ bb, const float* __restrict__ w,
                      const float* __restrict__ lam, float* __restrict__ ws)
{
  __shared__ float s_w[64], s_sw[64], s_bw[24], s_barb[64][24];
  __shared__ float s_BtB[64];
  __shared__ float s_G[64], s_g[8], s_wsum;
  const int t = threadIdx.x;
  s_w[t]  = w[t];
  s_sw[t] = sqrtf(fmaxf(s_w[t], 0.0f));
  __syncthreads();
  if (t == 0) { float a = 0; for (int n = 0; n < 64; n++) a += s_w[n]; s_wsum = a; }
  __syncthreads();
  const float wsum = s_wsum;
  if (t < 24) {                       // b_w[k*3+m]
    float a = 0;
    for (int n = 0; n < 64; n++) a += bb[t*64 + n] * s_w[n];
    s_bw[t] = a / wsum;
  }
  __syncthreads();
  for (int km = 0; km < 24; ++km)     // bar_b[n][km], t = n
    s_barb[t][km] = s_sw[t] * (bb[km*64 + t] - s_bw[km]);
  __syncthreads();
  {                                    // BtB, t = k*8+k2
    int k = t >> 3, k2 = t & 7;
    float a = 0;
    for (int n = 0; n < 64; n++)
      for (int j = 0; j < 3; j++)
        a += s_barb[n][k*3 + j] * s_barb[n][k2*3 + j];
    s_BtB[t] = a;
  }
  __syncthreads();
  if (t == 0) {
    const float lv = lam[0];
    float A[8][8], Iv[8][8];
#pragma unroll
    for (int i = 0; i < 8; i++)
#pragma unroll
      for (int j = 0; j < 8; j++) {
        A[i][j]  = 2.0f * (s_BtB[i*8 + j] + ((i == j) ? lv : 0.0f));
        Iv[i][j] = (i == j) ? 1.0f : 0.0f;
      }
#pragma unroll
    for (int k = 0; k < 8; k++) {
      float piv = 1.0f / A[k][k];
#pragma unroll
      for (int j = 0; j < 8; j++) { A[k][j] *= piv; Iv[k][j] *= piv; }
#pragma unroll
      for (int i = 0; i < 8; i++) {
        if (i == k) continue;
        float f = A[i][k];
#pragma unroll
        for (int j = 0; j < 8; j++) { A[i][j] -= f * A[k][j]; Iv[i][j] -= f * Iv[k][j]; }
      }
    }
    float u[8]; float s = 0;
#pragma unroll
    for (int i = 0; i < 8; i++) {
      float a = 0;
#pragma unroll
      for (int j = 0; j < 8; j++) a += Iv[i][j];
      u[i] = a; s += a;
    }
#pragma unroll
    for (int i = 0; i < 8; i++) s_g[i] = u[i] / s;
    float q00 = 0.0f;
#pragma unroll
    for (int i = 0; i < 8; i++)
#pragma unroll
      for (int j = 0; j < 8; j++) {
        s_G[i*8 + j] = Iv[i][j] - u[i]*u[j]/s;
        q00 += s_g[i] * (s_BtB[i*8 + j] + ((i == j) ? lv : 0.0f)) * s_g[j];
      }
    ws[WS_Q00]  = q00;
    ws[WS_WSUM] = wsum;
  }
  __syncthreads();
  if (t < 8)  ws[WS_g + t]  = s_g[t];
  if (t < 24) ws[WS_BW + t] = s_bw[t];
  ws[WS_G + t] = s_G[t];
  {                                     // packed per-n coefficients, t = n
    float* c = ws + WS_COEF + t*28;
    c[0] = s_w[t];
    float qc[3] = {0, 0, 0};
#pragma unroll
    for (int km = 0; km < 24; km++) {
      float cb = s_sw[t] * s_barb[t][km];
      c[4 + km] = cb;
      qc[km % 3] += s_g[km / 3] * cb;
    }
    c[1] = qc[0]; c[2] = qc[1]; c[3] = qc[2];
  }
}

// ---------------- K2: per-batch Q build ----------------
__global__ __launch_bounds__(256) void k_build(const float* __restrict__ y, float* ws)
{
  const int b = blockIdx.x * 256 + threadIdx.x;
  const float* yb = y + (size_t)b * 192;
  const float* coef = ws + WS_COEF;
  float F[24][3];
  float qt[3][3];
  float gw[6];
  float ywa[3] = {0, 0, 0};
#pragma unroll
  for (int i = 0; i < 24; i++) { F[i][0] = 0; F[i][1] = 0; F[i][2] = 0; }
#pragma unroll
  for (int i = 0; i < 9; i++) qt[i/3][i%3] = 0;
#pragma unroll
  for (int i = 0; i < 6; i++) gw[i] = 0;

  for (int n4 = 0; n4 < 16; n4++) {
    float4 v0 = reinterpret_cast<const float4*>(yb)[n4];
    float4 v1 = reinterpret_cast<const float4*>(yb + 64)[n4];
    float4 v2 = reinterpret_cast<const float4*>(yb + 128)[n4];
    float a0[4] = {v0.x, v0.y, v0.z, v0.w};
    float a1[4] = {v1.x, v1.y, v1.z, v1.w};
    float a2[4] = {v2.x, v2.y, v2.z, v2.w};
#pragma unroll
    for (int l = 0; l < 4; l++) {
      const int n = 4*n4 + l;
      const float* c = coef + n*28;
      float ym0 = a0[l], ym1 = a1[l], ym2 = a2[l];
      float wn  = c[0];
      float wy0 = wn*ym0, wy1 = wn*ym1, wy2 = wn*ym2;
      ywa[0] += wy0; ywa[1] += wy1; ywa[2] += wy2;
      gw[0] += wy0*ym0; gw[1] += wy0*ym1; gw[2] += wy0*ym2;
      gw[3] += wy1*ym1; gw[4] += wy1*ym2; gw[5] += wy2*ym2;
#pragma unroll
      for (int j = 0; j < 3; j++) {
        float qcv = c[1 + j];
        qt[j][0] += qcv*ym0; qt[j][1] += qcv*ym1; qt[j][2] += qcv*ym2;
      }
#pragma unroll
      for (int kj = 0; kj < 24; kj++) {
        float cb = c[4 + kj];
        F[kj][0] += cb*ym0; F[kj][1] += cb*ym1; F[kj][2] += cb*ym2;
      }
    }
  }
  const float wsum = ws[WS_WSUM];
  const float q00  = ws[WS_Q00];
  const float iws  = 1.0f / wsum;
  float yw[3] = {ywa[0]*iws, ywa[1]*iws, ywa[2]*iws};
  float Gram[3][3];
  Gram[0][0] = gw[0] - ywa[0]*ywa[0]*iws;
  Gram[0][1] = Gram[1][0] = gw[1] - ywa[0]*ywa[1]*iws;
  Gram[0][2] = Gram[2][0] = gw[2] - ywa[0]*ywa[2]*iws;
  Gram[1][1] = gw[3] - ywa[1]*ywa[1]*iws;
  Gram[1][2] = Gram[2][1] = gw[4] - ywa[1]*ywa[2]*iws;
  Gram[2][2] = gw[5] - ywa[2]*ywa[2]*iws;

  float Gm[64];
#pragma unroll
  for (int i = 0; i < 64; i++) Gm[i] = ws[WS_G + i];
  float FG[8][9];
#pragma unroll
  for (int k2 = 0; k2 < 8; k2++)
#pragma unroll
    for (int e = 0; e < 9; e++) {
      const int j = e / 3, m = e % 3;
      float a = 0;
#pragma unroll
      for (int k = 0; k < 8; k++) a += Gm[k*8 + k2] * F[k*3 + j][m];
      FG[k2][e] = a;
    }
  float q[55];
  q[tidx(0,0)] = q00;
#pragma unroll
  for (int e = 0; e < 9; e++) q[tidx(0, 1 + e)] = -qt[e/3][e%3];
#pragma unroll
  for (int e = 0; e < 9; e++)
#pragma unroll
    for (int f = e; f < 9; f++) {
      const int j = e/3, m = e%3, j2 = f/3, m2 = f%3;
      float a = 0;
#pragma unroll
      for (int k = 0; k < 8; k++) a += FG[k][e] * F[k*3 + j2][m2];
      q[tidx(1 + e, 1 + f)] = -2.0f*a + ((j == j2) ? Gram[m][m2] : 0.0f);
    }
  float* wb = ws + WS_BATCH;
#pragma unroll
  for (int i = 0; i < 55; i++) wb[(size_t)i*Bn + b] = q[i];
#pragma unroll
  for (int k = 0; k < 8; k++)
#pragma unroll
    for (int e = 0; e < 9; e++)
      wb[(size_t)(55 + k*9 + e)*Bn + b] = FG[k][e];
#pragma unroll
  for (int m = 0; m < 3; m++) wb[(size_t)(127 + m)*Bn + b] = yw[m];
}

// ---------------- K3: eigenvalue-only Jacobi + Cholesky inverse iteration ----------------
__global__ __launch_bounds__(64, 1) void k_eig(const float* __restrict__ ws,
                                               float* __restrict__ out)
{
  const int b = blockIdx.x * 64 + threadIdx.x;
  const float* wb = ws + WS_BATCH;

  // ---- phase A: eigenvalues via cyclic Jacobi on packed A[55] (no V) ----
  float A[55];
  float tr = 0.0f;
#pragma unroll
  for (int i = 0; i < 55; i++) A[i] = wb[(size_t)i*Bn + b];
#pragma unroll
  for (int j = 0; j < 10; j++) tr += A[tidx(j,j)];

  for (int sweep = 0; sweep < NSWEEP; ++sweep) {
#pragma unroll
    for (int p = 0; p < 10; p++) {
#pragma unroll
      for (int q = p + 1; q < 10; q++) {
        float apq = A[tidx(p,q)];
        float app = A[tidx(p,p)];
        float aqq = A[tidx(q,q)];
        float theta = 0.5f * (aqq - app) * __builtin_amdgcn_rcpf(apq);
        float tt = __builtin_amdgcn_rcpf(fabsf(theta) +
                     __builtin_amdgcn_sqrtf(theta*theta + 1.0f));
        tt = (theta < 0.0f) ? -tt : tt;
        tt = (fabsf(apq) <= 1e-30f) ? 0.0f : tt;     // guard NaN/degenerate
        float cth = __builtin_amdgcn_rsqf(tt*tt + 1.0f);
        float sth = tt * cth;
        A[tidx(p,p)] = app - tt*apq;
        A[tidx(q,q)] = aqq + tt*apq;
        A[tidx(p,q)] = 0.0f;
#pragma unroll
        for (int i = 0; i < 10; i++) {
          if (i == p || i == q) continue;
          float aip = A[tmm(i,p)];
          float aiq = A[tmm(i,q)];
          A[tmm(i,p)] = cth*aip - sth*aiq;
          A[tmm(i,q)] = sth*aip + cth*aiq;
        }
      }
    }
  }
  float lmin = A[tidx(0,0)];
#pragma unroll
  for (int j = 1; j < 10; j++) lmin = fminf(lmin, A[tidx(j,j)]);

  // ---- phase B: eigenvector via Cholesky of (Q - sigma I) + inverse iteration ----
  const float delta = 1e-5f * fabsf(tr) + 1e-30f;
  const float sigma = lmin - delta;
  float M[55];                 // packed lower, overwritten by L (rows scaled later by id)
  float id[10];
#pragma unroll
  for (int i = 0; i < 10; i++)
#pragma unroll
    for (int j = 0; j <= i; j++)
      M[lidx(i,j)] = wb[(size_t)tidx(j,i)*Bn + b] - ((i == j) ? sigma : 0.0f);
#pragma unroll
  for (int j = 0; j < 10; j++) {
    float d = M[lidx(j,j)];
#pragma unroll
    for (int t2 = 0; t2 < j; t2++) d -= M[lidx(j,t2)] * M[lidx(j,t2)];
    d = fmaxf(d, 1e-30f);
    float is = __builtin_amdgcn_rsqf(d);
    id[j] = is;
    M[lidx(j,j)] = d * is;     // = sqrt(d) = L[j][j] (kept for clarity; solves use id)
#pragma unroll
    for (int i = j + 1; i < 10; i++) {
      float a = M[lidx(i,j)];
#pragma unroll
      for (int t2 = 0; t2 < j; t2++) a -= M[lidx(i,t2)] * M[lidx(j,t2)];
      M[lidx(i,j)] = a * is;
    }
  }

  float x[10];
#pragma unroll
  for (int i = 0; i < 10; i++) x[i] = 1.0f;

#pragma unroll
  for (int it = 0; it < 3; ++it) {
    // forward: L z = x  (in place into x)
#pragma unroll
    for (int i = 0; i < 10; i++) {
      float a = x[i];
#pragma unroll
      for (int j = 0; j < i; j++) a -= M[lidx(i,j)] * x[j];
      x[i] = a * id[i];
    }
    // backward: L^T v = z  (in place into x)
#pragma unroll
    for (int i = 9; i >= 0; i--) {
      float a = x[i];
#pragma unroll
      for (int j = i + 1; j < 10; j++) a -= M[lidx(j,i)] * x[j];
      x[i] = a * id[i];
    }
    // renormalize to avoid overflow
    float s2 = 0;
#pragma unroll
    for (int i = 0; i < 10; i++) s2 += x[i]*x[i];
    float sc = __builtin_amdgcn_rsqf(s2 + 1e-38f);
#pragma unroll
    for (int i = 0; i < 10; i++) x[i] *= sc;
  }

  // ---- epilogue: R, t, c ----
  const float inv0 = __builtin_amdgcn_rcpf(x[0]);
  float R[3][3];
#pragma unroll
  for (int r = 0; r < 3; r++)
#pragma unroll
    for (int cc = 0; cc < 3; cc++)
      R[r][cc] = x[1 + 3*cc + r] * inv0;
  float cvec[8];
#pragma unroll
  for (int k = 0; k < 8; k++) {
    float a = 0;
#pragma unroll
    for (int e = 0; e < 9; e++) a += x[1 + e] * wb[(size_t)(55 + k*9 + e)*Bn + b];
    cvec[k] = 2.0f * inv0 * a + ws[WS_g + k];
  }
  float um[3] = {0, 0, 0};
#pragma unroll
  for (int k = 0; k < 8; k++) {
    float ck = cvec[k];
    um[0] += ws[WS_BW + k*3 + 0] * ck;
    um[1] += ws[WS_BW + k*3 + 1] * ck;
    um[2] += ws[WS_BW + k*3 + 2] * ck;
  }
#pragma unroll
  for (int r = 0; r < 3; r++)
#pragma unroll
    for (int cc = 0; cc < 3; cc++)
      out[(size_t)b*9 + r*3 + cc] = R[r][cc];
#pragma unroll
  for (int r = 0; r < 3; r++) {
    float yw = wb[(size_t)(127 + r)*Bn + b];
    out[(size_t)9*Bn + b*3 + r] = yw - (R[r][0]*um[0] + R[r][1]*um[1] + R[r][2]*um[2]);
  }
#pragma unroll
  for (int k = 0; k < 8; k++)
    out[(size_t)12*Bn + b*8 + k] = cvec[k];
}

extern "C" void kernel_launch(void* const* d_in, const int* in_sizes, int n_in,
                              void* d_out, int out_size, void* d_ws, size_t ws_size,
                              hipStream_t stream) {
  const float* y   = (const float*)d_in[0];
  const float* bb  = (const float*)d_in[1];
  const float* w   = (const float*)d_in[2];
  const float* lam = (const float*)d_in[3];
  float* ws  = (float*)d_ws;
  float* out = (float*)d_out;
  k_pre  <<<1,        64, 0, stream>>>(bb, w, lam, ws);
  k_build<<<Bn/256,  256, 0, stream>>>(y, ws);
  k_eig  <<<Bn/64,    64, 0, stream>>>(ws, out);
}